// Round 8
// baseline (450.399 us; speedup 1.0000x reference)
//
#include <hip/hip_runtime.h>
#include <hip/hip_bf16.h>

typedef __attribute__((ext_vector_type(8))) unsigned short u16x8;
typedef __attribute__((ext_vector_type(8))) __bf16 bf16x8;
typedef __attribute__((ext_vector_type(4))) float f32x4;

#define CSR_NB 256

// pack two f32 -> two bf16 (round-half-up): 2 adds + 1 v_perm_b32
__device__ __forceinline__ unsigned pack_bf2(float lo, float hi) {
  unsigned a = __float_as_uint(lo) + 0x8000u;
  unsigned b = __float_as_uint(hi) + 0x8000u;
  return __builtin_amdgcn_perm(b, a, 0x07060302);
}

__device__ __forceinline__ unsigned short f2bf(float f) {
  unsigned u = __float_as_uint(f);
  return (unsigned short)((u + 0x7fffu + ((u >> 16) & 1u)) >> 16);  // RNE (prep only)
}

// swizzled byte offset into a [rows][stride bytes] bf16 buffer (16B-chunk XOR by row&7)
__device__ __forceinline__ int aswz(int row, int feat, int stride) {
  return row * stride + (((feat >> 3) ^ (row & 7)) << 4) + (feat & 7) * 2;
}

// device-wide spin barrier; counters pre-zeroed by host memset each call
__device__ __forceinline__ void gbar(int* bar, int id) {
  __threadfence();
  __syncthreads();
  if (threadIdx.x == 0) {
    __hip_atomic_fetch_add(&bar[id], 1, __ATOMIC_ACQ_REL, __HIP_MEMORY_SCOPE_AGENT);
    while (__hip_atomic_load(&bar[id], __ATOMIC_ACQUIRE, __HIP_MEMORY_SCOPE_AGENT) < CSR_NB)
      __builtin_amdgcn_s_sleep(2);
  }
  __syncthreads();
}

// ---- fused CSR build: weights + hist + zero-out | scan | tops | fill ----
__global__ __launch_bounds__(256)
void csr_build(const float* __restrict__ W1, const float* __restrict__ W2,
               const float* __restrict__ W3, const float* __restrict__ W4,
               unsigned short* __restrict__ wt, const int* __restrict__ ei,
               int* __restrict__ histI, int* __restrict__ row_start,
               int* __restrict__ blockSums, int* __restrict__ wcnt,
               int2* __restrict__ edlist, float* __restrict__ out,
               int* __restrict__ bar, int E, int N) {
  const int tid = blockIdx.x * 256 + threadIdx.x;
  const int lane = threadIdx.x & 63, w = threadIdx.x >> 6;
  const int NTH = CSR_NB * 256;
  __shared__ int wsum[4];

  // P1a: weight transpose/pack (pre-swizzled)
  if (tid < 22528) {
    float v; int n, k, K, base;
    if (tid < 4096)       { n = tid >> 6, k = tid & 63;  K = 64;  base = 0;     v = W1[k * 64 + n]; }
    else if (tid < 12288) { int j = tid - 4096;  n = j >> 6, k = j & 63;  K = 64;  base = 4096;  v = W2[k * 128 + n]; }
    else if (tid < 20480) { int j = tid - 12288; n = j >> 7, k = j & 127; K = 128; base = 12288; v = W3[k * 64 + n]; }
    else                  { int j = tid - 20480; n = j >> 6, k = j & 63;  K = 64;  base = 20480; v = W4[k * 32 + n]; }
    int o = base + n * K + ((((k >> 3) ^ (n & 7)) << 3) + (k & 7));
    wt[o] = f2bf(v);
  }
  // P1b: zero the output
  const int Ntot4 = N * 8;  // N*32/4
  for (int i = tid; i < Ntot4; i += NTH)
    ((float4*)out)[i] = make_float4(0.f, 0.f, 0.f, 0.f);
  // P1c: degree histogram (4 edges/thread)
  for (int e0 = tid * 4; e0 < E; e0 += NTH * 4) {
    if (e0 + 3 < E) {
      const int4 d4 = *(const int4*)(ei + E + e0);
      atomicAdd(&histI[d4.x], 1); atomicAdd(&histI[d4.y], 1);
      atomicAdd(&histI[d4.z], 1); atomicAdd(&histI[d4.w], 1);
    } else {
      for (int e = e0; e < E; ++e) atomicAdd(&histI[ei[E + e]], 1);
    }
  }
  gbar(bar, 0);

  // P2a: per-block local exclusive scan (256 elems/block, 1/thread)
  const int i = tid;
  const int v = (i < N) ? histI[i] : 0;
  int s = v;
#pragma unroll
  for (int d = 1; d < 64; d <<= 1) { int t = __shfl_up(s, d, 64); if (lane >= d) s += t; }
  if (lane == 63) wsum[w] = s;
  __syncthreads();
  int wOff = 0;
#pragma unroll
  for (int k = 0; k < 4; ++k) if (k < w) wOff += wsum[k];
  const int lexcl = wOff + (s - v);
  if (threadIdx.x == 0) {
    int bt = wsum[0] + wsum[1] + wsum[2] + wsum[3];
    blockSums[blockIdx.x] = bt;
  }
  gbar(bar, 1);

  // P2b: block 0, wave 0 scans 256 block sums -> exclusive
  if (blockIdx.x == 0 && threadIdx.x < 64) {
    int run = 0;
    for (int c = 0; c < 4; ++c) {
      const int idx = c * 64 + lane;
      const int bv = blockSums[idx];
      int bs = bv;
#pragma unroll
      for (int d = 1; d < 64; d <<= 1) { int t = __shfl_up(bs, d, 64); if (lane >= d) bs += t; }
      const int ctot = __shfl(bs, 63, 64);
      blockSums[idx] = run + bs - bv;
      run += ctot;
    }
    if (lane == 0) row_start[N] = E;
  }
  gbar(bar, 2);

  // P2c: finalize row_start
  if (i < N) row_start[i] = blockSums[blockIdx.x] + lexcl;
  gbar(bar, 3);

  // P3: fill CSR edge list
  for (int e0 = tid * 4; e0 < E; e0 += NTH * 4) {
    if (e0 + 3 < E) {
      const int4 d4 = *(const int4*)(ei + E + e0);
      const int dv[4] = {d4.x, d4.y, d4.z, d4.w};
#pragma unroll
      for (int j = 0; j < 4; ++j) {
        const int d = dv[j];
        const int slot = atomicAdd(&wcnt[d], 1);
        edlist[row_start[d] + slot] = make_int2(e0 + j, d);
      }
    } else {
      for (int e = e0; e < E; ++e) {
        const int d = ei[E + e];
        const int slot = atomicAdd(&wcnt[d], 1);
        edlist[row_start[d] + slot] = make_int2(e, d);
      }
    }
  }
}

// ---- one MLP layer: dst = relu(W^T srcH + b); weights read from LDS ----
template <int MT, int KS, int SS, int DS>
__device__ __forceinline__ void mlp_layer(const unsigned char* src, unsigned char* dst,
                                          const unsigned char* wl, const float* biasL, int lane) {
  const int edge = lane & 15, g = lane >> 4;
  asm volatile("s_waitcnt lgkmcnt(0)" ::: "memory");
  u16x8 bfrag[KS];
#pragma unroll
  for (int ks = 0; ks < KS; ++ks)
    bfrag[ks] = *(const u16x8*)(src + aswz(edge, ks * 32 + g * 8, SS));
#pragma unroll
  for (int mt = 0; mt < MT; ++mt) {
    const int n = mt * 16 + edge;
    u16x8 af[KS];
#pragma unroll
    for (int ks = 0; ks < KS; ++ks)
      af[ks] = *(const u16x8*)(wl + n * (KS * 64) + (((ks * 4 + g) ^ (edge & 7)) << 4));
    const float4 bv = *(const float4*)(biasL + mt * 16 + g * 4);
    f32x4 acc = {bv.x, bv.y, bv.z, bv.w};
    __builtin_amdgcn_s_setprio(1);
#pragma unroll
    for (int ks = 0; ks < KS; ++ks)
      acc = __builtin_amdgcn_mfma_f32_16x16x32_bf16(
          __builtin_bit_cast(bf16x8, af[ks]), __builtin_bit_cast(bf16x8, bfrag[ks]),
          acc, 0, 0, 0);
    __builtin_amdgcn_s_setprio(0);
    const int fb = mt * 16 + g * 4;
    uint2 q;
    q.x = pack_bf2(fmaxf(acc[0], 0.f), fmaxf(acc[1], 0.f));
    q.y = pack_bf2(fmaxf(acc[2], 0.f), fmaxf(acc[3], 0.f));
    *(uint2*)(dst + aswz(edge, fb, DS)) = q;
  }
}

// gather one tile (CSR positions pbase..pbase+15, clipped at pend)
__device__ __forceinline__ void load_tile(int pbase, int pend, const int2* __restrict__ edlist,
                                          const float* __restrict__ x, const float* __restrict__ ea,
                                          int lane, float4& xa, float4& xb, float4& ya, float4& yb,
                                          int& dstA) {
  const int el = pbase + (lane >> 2);
  const int part = lane & 3;
  xa = make_float4(0.f, 0.f, 0.f, 0.f); xb = xa; ya = xa; yb = xa;
  if (el < pend) {
    const int2 ed = edlist[el];
    const float4* xp = (const float4*)(x + (size_t)ed.y * 32 + part * 8);
    xa = xp[0]; xb = xp[1];
    const float4* ep = (const float4*)(ea + (size_t)ed.x * 32 + part * 8);
    ya = ep[0]; yb = ep[1];
  }
  const int pos = pbase + (lane & 15);
  dstA = (pos < pend) ? edlist[pos].y : -1;
}

__device__ __forceinline__ int lbound(const int* __restrict__ rs, int N, long tgt) {
  int lo = 0, hi = N;
  while (lo < hi) { int mid = (lo + hi) >> 1; if ((long)rs[mid] < tgt) lo = mid + 1; else hi = mid; }
  return lo;
}

// LDS layout: [weights 45056][bias 1152][16 waves x (buf0 4096 + buf1 2048)]
#define BIAS_OFF 45056
#define ACT_OFF  46208

__global__ __launch_bounds__(1024, 4)
void gnn_main(const float* __restrict__ x, const int2* __restrict__ edlist,
              const float* __restrict__ ea, const unsigned short* __restrict__ wt,
              const int* __restrict__ row_start,
              const float* __restrict__ b1, const float* __restrict__ b2,
              const float* __restrict__ b3, const float* __restrict__ b4,
              float* __restrict__ out, int E, int N) {
  __shared__ __align__(16) unsigned char lds[ACT_OFF + 16 * 6144];
  {
    const u16x8* gw = (const u16x8*)wt;
    u16x8* lw = (u16x8*)lds;
    for (int i = threadIdx.x; i < 2816; i += 1024) lw[i] = gw[i];
    float* biasW = (float*)(lds + BIAS_OFF);
    for (int i = threadIdx.x; i < 288; i += 1024) {
      float v;
      if (i < 64) v = b1[i];
      else if (i < 192) v = b2[i - 64];
      else if (i < 256) v = b3[i - 192];
      else v = b4[i - 256];
      biasW[i] = v;
    }
  }
  __syncthreads();

  const int lane = threadIdx.x & 63, wid = threadIdx.x >> 6;
  const int li = lane & 15, g = lane >> 4;
  const float* biasLds = (const float*)(lds + BIAS_OFF);
  unsigned char* buf0 = lds + ACT_OFF + wid * 6144;
  unsigned char* buf1 = buf0 + 4096;
  const unsigned char* wl1 = lds;
  const unsigned char* wl2 = lds + 8192;
  const unsigned char* wl3 = lds + 24576;
  const unsigned char* wl4 = lds + 40960;

  // ---- node-range assignment (edge-balanced, rounded to node boundaries) ----
  const int wgl = blockIdx.x * 16 + wid;
  const int W = gridDim.x * 16;
  const int n0 = lbound(row_start, N, (long)wgl * E / W);
  const int n1 = lbound(row_start, N, (long)(wgl + 1) * E / W);
  const int pstart = row_start[n0];
  const int pend = row_start[n1];

  float4 xa, xb, ya, yb; int dstA = -1;
  if (pstart < pend) load_tile(pstart, pend, edlist, x, ea, lane, xa, xb, ya, yb, dstA);

  float carry[8];
#pragma unroll
  for (int t = 0; t < 8; ++t) carry[t] = 0.f;
  int cDst = -1, cCnt = 0;

  for (int pbase = pstart; pbase < pend; pbase += 16) {
    // ---- stage H0 = concat(x[dst], edge_attr) as bf16 [16][64] ----
    uint4 hx, he;
    hx.x = pack_bf2(xa.x, xa.y); hx.y = pack_bf2(xa.z, xa.w);
    hx.z = pack_bf2(xb.x, xb.y); hx.w = pack_bf2(xb.z, xb.w);
    he.x = pack_bf2(ya.x, ya.y); he.y = pack_bf2(ya.z, ya.w);
    he.z = pack_bf2(yb.x, yb.y); he.w = pack_bf2(yb.z, yb.w);
    const int e2 = lane >> 2, part = lane & 3;
    *(uint4*)(buf0 + aswz(e2, part * 8, 256)) = hx;
    *(uint4*)(buf0 + aswz(e2, 32 + part * 8, 256)) = he;

    const int curDst = dstA;

    // ---- prefetch next tile ----
    const int np = pbase + 16;
    float4 nxa, nxb, nya, nyb; int nd = -1;
    if (np < pend) load_tile(np, pend, edlist, x, ea, lane, nxa, nxb, nya, nyb, nd);
    else { nxa = make_float4(0,0,0,0); nxb = nxa; nya = nxa; nyb = nxa; }

    mlp_layer<4, 2, 256, 128>(buf0, buf1, wl1, biasLds + 0,   lane);   // 64 -> 64
    mlp_layer<8, 2, 128, 256>(buf1, buf0, wl2, biasLds + 64,  lane);   // 64 -> 128
    mlp_layer<4, 4, 256, 128>(buf0, buf1, wl3, biasLds + 192, lane);   // 128 -> 64

    // ---- layer 4 ----
    asm volatile("s_waitcnt lgkmcnt(0)" ::: "memory");
    u16x8 bf4[2];
#pragma unroll
    for (int ks = 0; ks < 2; ++ks)
      bf4[ks] = *(const u16x8*)(buf1 + aswz(li, ks * 32 + g * 8, 128));
    float vals[8];
#pragma unroll
    for (int mt = 0; mt < 2; ++mt) {
      const int n = mt * 16 + li;
      u16x8 af[2];
#pragma unroll
      for (int ks = 0; ks < 2; ++ks)
        af[ks] = *(const u16x8*)(wl4 + n * 128 + (((ks * 4 + g) ^ (li & 7)) << 4));
      const float4 bv = *(const float4*)(biasLds + 256 + mt * 16 + g * 4);
      f32x4 acc = {bv.x, bv.y, bv.z, bv.w};
      __builtin_amdgcn_s_setprio(1);
#pragma unroll
      for (int ks = 0; ks < 2; ++ks)
        acc = __builtin_amdgcn_mfma_f32_16x16x32_bf16(
            __builtin_bit_cast(bf16x8, af[ks]), __builtin_bit_cast(bf16x8, bf4[ks]),
            acc, 0, 0, 0);
      __builtin_amdgcn_s_setprio(0);
#pragma unroll
      for (int r = 0; r < 4; ++r) vals[mt * 4 + r] = fmaxf(acc[r], 0.f);
    }

    // ---- aggregation: fast path (whole tile continues the open node) ----
    if (__all(curDst == cDst)) {
#pragma unroll
      for (int t = 0; t < 8; ++t) carry[t] += vals[t];
      cCnt += 16;
    } else {
      // heads / segment distances
      const int prev = __shfl_up(curDst, 1, 16);
      const bool is_head = (li == 0) || (prev != curDst);
      const unsigned long long hb = __ballot(is_head);
      const unsigned gm = (unsigned)((hb >> (g * 16)) & 0xFFFFu);
      const unsigned below = gm & ((1u << li) | ((1u << li) - 1u));
      const int dist = li - (31 - __clz(below));

      // carried-node total (butterfly over the 16-lane group)
      float ctot[8];
#pragma unroll
      for (int t = 0; t < 8; ++t) {
        float c = carry[t];
#pragma unroll
        for (int d = 1; d < 16; d <<= 1) c += __shfl_xor(c, d, 16);
        ctot[t] = c;
      }

      // orphan: open node ended exactly at previous tile boundary
      const int dst0 = __shfl(curDst, lane & 48, 64);
      if (cDst >= 0 && dst0 != cDst && li == 0) {
        const float inv = 1.0f / (float)cCnt;
        float4 o0 = {ctot[0] * inv, ctot[1] * inv, ctot[2] * inv, ctot[3] * inv};
        float4 o1 = {ctot[4] * inv, ctot[5] * inv, ctot[6] * inv, ctot[7] * inv};
        *(float4*)(out + (size_t)cDst * 32 + g * 4) = o0;
        *(float4*)(out + (size_t)cDst * 32 + 16 + g * 4) = o1;
      }

      // segmented inclusive scan (in place)
#pragma unroll
      for (int d = 1; d < 16; d <<= 1) {
#pragma unroll
        for (int t = 0; t < 8; ++t) {
          const float tv = __shfl_up(vals[t], d, 16);
          if (dist >= d) vals[t] += tv;
        }
      }

      const int ndst0 = __shfl(nd, lane & 48, 64);
      const bool is_end = (li == 15) || ((gm >> (li + 1)) & 1u);
      const bool complete = (li < 15) || (curDst != ndst0);
      const bool firstAdd = (dist == li) && (curDst == cDst) && (cDst >= 0);
      if (is_end && curDst >= 0 && complete) {
        const int cnt = dist + 1 + (firstAdd ? cCnt : 0);
        const float inv = 1.0f / (float)cnt;
        float tot[8];
#pragma unroll
        for (int t = 0; t < 8; ++t) tot[t] = (vals[t] + (firstAdd ? ctot[t] : 0.f)) * inv;
        float4 o0 = {tot[0], tot[1], tot[2], tot[3]};
        float4 o1 = {tot[4], tot[5], tot[6], tot[7]};
        *(float4*)(out + (size_t)curDst * 32 + g * 4) = o0;
        *(float4*)(out + (size_t)curDst * 32 + 16 + g * 4) = o1;
      }

      // carry update (lane15 representation: total lives in lane 15, others 0)
      const int dst15 = __shfl(curDst, lane | 15, 64);
      const int d15 = __shfl(dist, lane | 15, 64);
      const bool inc15 = (dst15 >= 0) && (dst15 == ndst0);
      if (inc15) {
#pragma unroll
        for (int t = 0; t < 8; ++t)
          carry[t] = (li == 15) ? (vals[t] + (firstAdd ? ctot[t] : 0.f)) : 0.f;
        cCnt = d15 + 1 + ((d15 == 15 && dst15 == cDst) ? cCnt : 0);
        cDst = dst15;
      } else {
#pragma unroll
        for (int t = 0; t < 8; ++t) carry[t] = 0.f;
        cCnt = 0; cDst = -1;
      }
    }

    xa = nxa; xb = nxb; ya = nya; yb = nyb; dstA = nd;
  }

  // ---- final flush of an open node ----
  if (cDst >= 0) {
    float ctot[8];
#pragma unroll
    for (int t = 0; t < 8; ++t) {
      float c = carry[t];
#pragma unroll
      for (int d = 1; d < 16; d <<= 1) c += __shfl_xor(c, d, 16);
      ctot[t] = c;
    }
    if (li == 0) {
      const float inv = 1.0f / (float)cCnt;
      float4 o0 = {ctot[0] * inv, ctot[1] * inv, ctot[2] * inv, ctot[3] * inv};
      float4 o1 = {ctot[4] * inv, ctot[5] * inv, ctot[6] * inv, ctot[7] * inv};
      *(float4*)(out + (size_t)cDst * 32 + g * 4) = o0;
      *(float4*)(out + (size_t)cDst * 32 + 16 + g * 4) = o1;
    }
  }
}

extern "C" void kernel_launch(void* const* d_in, const int* in_sizes, int n_in,
                              void* d_out, int out_size, void* d_ws, size_t ws_size,
                              hipStream_t stream) {
  const float* x  = (const float*)d_in[0];
  const int*   ei = (const int*)d_in[1];
  const float* ea = (const float*)d_in[2];
  const float* W1 = (const float*)d_in[3];
  const float* b1 = (const float*)d_in[4];
  const float* W2 = (const float*)d_in[5];
  const float* b2 = (const float*)d_in[6];
  const float* W3 = (const float*)d_in[7];
  const float* b3 = (const float*)d_in[8];
  const float* W4 = (const float*)d_in[9];
  const float* b4 = (const float*)d_in[10];
  const int N = in_sizes[0] / 32;
  const int E = in_sizes[1] / 2;
  float* out = (float*)d_out;

  char* ws = (char*)d_ws;
  size_t off = 0;
  auto alloc = [&](size_t bytes) { size_t o = off; off += (bytes + 255) & ~(size_t)255; return o; };
  size_t bar_off  = alloc(256);
  size_t hist_off = alloc((size_t)N * 4);
  size_t wcnt_off = alloc((size_t)N * 4);
  int* bar        = (int*)(ws + bar_off);
  int* histI      = (int*)(ws + hist_off);
  int* wcnt       = (int*)(ws + wcnt_off);
  int* row_start  = (int*)(ws + alloc((size_t)(N + 1) * 4));
  int* blockSums  = (int*)(ws + alloc(256 * 4));
  int2* edlist    = (int2*)(ws + alloc((size_t)E * 8));
  unsigned short* wt = (unsigned short*)(ws + alloc(22528 * 2));

  // one memset zeroes barriers + histI + wcnt (contiguous at ws start)
  hipMemsetAsync(ws, 0, wcnt_off + (size_t)N * 4, stream);

  csr_build<<<CSR_NB, 256, 0, stream>>>(W1, W2, W3, W4, wt, ei, histI, row_start,
                                        blockSums, wcnt, edlist, out, bar, E, N);
  gnn_main<<<512, 1024, 0, stream>>>(x, edlist, ea, wt, row_start,
                                     b1, b2, b3, b4, out, E, N);
}

// Round 10
// 341.775 us; speedup vs baseline: 1.3178x; 1.3178x over previous
//
#include <hip/hip_runtime.h>
#include <hip/hip_bf16.h>

typedef __attribute__((ext_vector_type(8))) unsigned short u16x8;
typedef __attribute__((ext_vector_type(8))) __bf16 bf16x8;
typedef __attribute__((ext_vector_type(4))) float f32x4;

// pack two f32 -> two bf16 (round-half-up): 2 adds + 1 v_perm_b32
__device__ __forceinline__ unsigned pack_bf2(float lo, float hi) {
  unsigned a = __float_as_uint(lo) + 0x8000u;
  unsigned b = __float_as_uint(hi) + 0x8000u;
  return __builtin_amdgcn_perm(b, a, 0x07060302);
}

__device__ __forceinline__ unsigned short f2bf(float f) {
  unsigned u = __float_as_uint(f);
  return (unsigned short)((u + 0x7fffu + ((u >> 16) & 1u)) >> 16);  // RNE (prep only)
}

// swizzled byte offset into a [rows][stride bytes] bf16 buffer (16B-chunk XOR by row&7)
__device__ __forceinline__ int aswz(int row, int feat, int stride) {
  return row * stride + (((feat >> 3) ^ (row & 7)) << 4) + (feat & 7) * 2;
}

// ---- weights transpose/pack + XCD-partitioned degree histogram ----
__global__ __launch_bounds__(256)
void prep_hist(const float* __restrict__ W1, const float* __restrict__ W2,
               const float* __restrict__ W3, const float* __restrict__ W4,
               unsigned short* __restrict__ wt,
               const int* __restrict__ ei, int* __restrict__ histI, int E, int N) {
  const int tid = threadIdx.x;
  const int i = blockIdx.x * 256 + tid;
  if (i < 22528) {
    float v; int n, k, K, base;
    if (i < 4096)       { n = i >> 6, k = i & 63;  K = 64;  base = 0;     v = W1[k * 64 + n]; }
    else if (i < 12288) { int j = i - 4096;  n = j >> 6, k = j & 63;  K = 64;  base = 4096;  v = W2[k * 128 + n]; }
    else if (i < 20480) { int j = i - 12288; n = j >> 7, k = j & 127; K = 128; base = 12288; v = W3[k * 64 + n]; }
    else                { int j = i - 20480; n = j >> 6, k = j & 63;  K = 64;  base = 20480; v = W4[k * 32 + n]; }
    int o = base + n * K + ((((k >> 3) ^ (n & 7)) << 3) + (k & 7));
    wt[o] = f2bf(v);
  }
  const int xcd = blockIdx.x & 7, kblk = blockIdx.x >> 3;
  const int nchunks = gridDim.x >> 3;
  const int chunk = (E + nchunks - 1) / nchunks;
  const int eBeg = kblk * chunk;
  const int eEnd = min(eBeg + chunk, E);
  const int dLo = (int)((long)xcd * N / 8);
  const int dHi = (int)((long)(xcd + 1) * N / 8);
  for (int e = eBeg + tid; e < eEnd; e += 256) {
    const int d = ei[E + e];
    if (d >= dLo && d < dHi) atomicAdd(&histI[d], 1);
  }
}

// per-block exclusive scan of 2048 elems (256 thr x 8), write per-block totals
__global__ void scan_blocks(const int* __restrict__ histI, int* __restrict__ row_start,
                            int* __restrict__ blockSums, int N) {
  __shared__ int wsum[4];
  const int lane = threadIdx.x & 63, w = threadIdx.x >> 6;
  const int i0 = blockIdx.x * 2048 + threadIdx.x * 8;
  int v[8];
#pragma unroll
  for (int j = 0; j < 8; ++j) { int i = i0 + j; v[j] = (i < N) ? histI[i] : 0; }
  int s = 0;
#pragma unroll
  for (int j = 0; j < 8; ++j) { int t = v[j]; v[j] = s; s += t; }
  int ss = s;
#pragma unroll
  for (int d = 1; d < 64; d <<= 1) { int t = __shfl_up(ss, d, 64); if (lane >= d) ss += t; }
  if (lane == 63) wsum[w] = ss;
  __syncthreads();
  int wOff = 0;
#pragma unroll
  for (int k = 0; k < 4; ++k) if (k < w) wOff += wsum[k];
  const int tOff = wOff + (ss - s);
#pragma unroll
  for (int j = 0; j < 8; ++j) { int i = i0 + j; if (i < N) row_start[i] = tOff + v[j]; }
  if (threadIdx.x == 255) blockSums[blockIdx.x] = wOff + ss;
}

// make row_start GLOBALLY exclusive (add block prefix) + sentinel
__global__ void scan_add(int* __restrict__ row_start, const int* __restrict__ blockSums,
                         int N, int E, int nb) {
  __shared__ int spre[32];
  if (threadIdx.x == 0) {
    int acc = 0;
    for (int k = 0; k < nb; ++k) { spre[k] = acc; acc += blockSums[k]; }
  }
  __syncthreads();
  const int i = blockIdx.x * 256 + threadIdx.x;
  if (i < N) row_start[i] += spre[i >> 11];
  if (i == 0) row_start[N] = E;
}

// ---- XCD-partitioned CSR fill (+ zero out); row_start is global-exclusive here ----
__global__ __launch_bounds__(256)
void fill_kernel(const int* __restrict__ ei, const int* __restrict__ row_start,
                 int* __restrict__ wcnt, int2* __restrict__ edlist,
                 float* __restrict__ out, int E, int N) {
  const int tid = threadIdx.x;
  const int Ntot4 = N * 8;
  for (int i = blockIdx.x * 256 + tid; i < Ntot4; i += gridDim.x * 256)
    ((float4*)out)[i] = make_float4(0.f, 0.f, 0.f, 0.f);

  const int xcd = blockIdx.x & 7, kblk = blockIdx.x >> 3;
  const int nchunks = gridDim.x >> 3;
  const int chunk = (E + nchunks - 1) / nchunks;
  const int eBeg = kblk * chunk;
  const int eEnd = min(eBeg + chunk, E);
  const int dLo = (int)((long)xcd * N / 8);
  const int dHi = (int)((long)(xcd + 1) * N / 8);
  for (int e = eBeg + tid; e < eEnd; e += 256) {
    const int d = ei[E + e];
    if (d >= dLo && d < dHi) {
      const int slot = atomicAdd(&wcnt[d], 1);
      edlist[row_start[d] + slot] = make_int2(e, d);
    }
  }
}

// ---- one MLP layer: dst = relu(W^T srcH + b); weights read from LDS ----
template <int MT, int KS, int SS, int DS>
__device__ __forceinline__ void mlp_layer(const unsigned char* src, unsigned char* dst,
                                          const unsigned char* wl, const float* biasL, int lane) {
  const int edge = lane & 15, g = lane >> 4;
  asm volatile("s_waitcnt lgkmcnt(0)" ::: "memory");
  u16x8 bfrag[KS];
#pragma unroll
  for (int ks = 0; ks < KS; ++ks)
    bfrag[ks] = *(const u16x8*)(src + aswz(edge, ks * 32 + g * 8, SS));
#pragma unroll
  for (int mt = 0; mt < MT; ++mt) {
    const int n = mt * 16 + edge;
    u16x8 af[KS];
#pragma unroll
    for (int ks = 0; ks < KS; ++ks)
      af[ks] = *(const u16x8*)(wl + n * (KS * 64) + (((ks * 4 + g) ^ (edge & 7)) << 4));
    const float4 bv = *(const float4*)(biasL + mt * 16 + g * 4);
    f32x4 acc = {bv.x, bv.y, bv.z, bv.w};
    __builtin_amdgcn_s_setprio(1);
#pragma unroll
    for (int ks = 0; ks < KS; ++ks)
      acc = __builtin_amdgcn_mfma_f32_16x16x32_bf16(
          __builtin_bit_cast(bf16x8, af[ks]), __builtin_bit_cast(bf16x8, bfrag[ks]),
          acc, 0, 0, 0);
    __builtin_amdgcn_s_setprio(0);
    const int fb = mt * 16 + g * 4;
    uint2 q;
    q.x = pack_bf2(fmaxf(acc[0], 0.f), fmaxf(acc[1], 0.f));
    q.y = pack_bf2(fmaxf(acc[2], 0.f), fmaxf(acc[3], 0.f));
    *(uint2*)(dst + aswz(edge, fb, DS)) = q;
  }
}

// gather one tile (CSR positions pbase..pbase+15, clipped at pend)
__device__ __forceinline__ void load_tile(int pbase, int pend, const int2* __restrict__ edlist,
                                          const float* __restrict__ x, const float* __restrict__ ea,
                                          int lane, float4& xa, float4& xb, float4& ya, float4& yb,
                                          int& dstA) {
  const int el = pbase + (lane >> 2);
  const int part = lane & 3;
  xa = make_float4(0.f, 0.f, 0.f, 0.f); xb = xa; ya = xa; yb = xa;
  if (el < pend) {
    const int2 ed = edlist[el];
    const float4* xp = (const float4*)(x + (size_t)ed.y * 32 + part * 8);
    xa = xp[0]; xb = xp[1];
    const float4* ep = (const float4*)(ea + (size_t)ed.x * 32 + part * 8);
    ya = ep[0]; yb = ep[1];
  }
  const int pos = pbase + (lane & 15);
  dstA = (pos < pend) ? edlist[pos].y : -1;
}

__device__ __forceinline__ int lbound(const int* __restrict__ rs, int N, long tgt) {
  int lo = 0, hi = N;
  while (lo < hi) { int mid = (lo + hi) >> 1; if ((long)rs[mid] < tgt) lo = mid + 1; else hi = mid; }
  return lo;
}

// LDS layout: [weights 45056][bias 1152][16 waves x (buf0 4096 + buf1 2048)]
#define BIAS_OFF 45056
#define ACT_OFF  46208

__global__ __launch_bounds__(1024, 4)
void gnn_main(const float* __restrict__ x, const int2* __restrict__ edlist,
              const float* __restrict__ ea, const unsigned short* __restrict__ wt,
              const int* __restrict__ row_start,
              const float* __restrict__ b1, const float* __restrict__ b2,
              const float* __restrict__ b3, const float* __restrict__ b4,
              float* __restrict__ out, int E, int N) {
  __shared__ __align__(16) unsigned char lds[ACT_OFF + 16 * 6144];
  {
    const u16x8* gw = (const u16x8*)wt;
    u16x8* lw = (u16x8*)lds;
    for (int i = threadIdx.x; i < 2816; i += 1024) lw[i] = gw[i];
    float* biasW = (float*)(lds + BIAS_OFF);
    for (int i = threadIdx.x; i < 288; i += 1024) {
      float v;
      if (i < 64) v = b1[i];
      else if (i < 192) v = b2[i - 64];
      else if (i < 256) v = b3[i - 192];
      else v = b4[i - 256];
      biasW[i] = v;
    }
  }
  __syncthreads();

  const int lane = threadIdx.x & 63, wid = threadIdx.x >> 6;
  const int li = lane & 15, g = lane >> 4;
  const float* biasLds = (const float*)(lds + BIAS_OFF);
  unsigned char* buf0 = lds + ACT_OFF + wid * 6144;
  unsigned char* buf1 = buf0 + 4096;
  const unsigned char* wl1 = lds;
  const unsigned char* wl2 = lds + 8192;
  const unsigned char* wl3 = lds + 24576;
  const unsigned char* wl4 = lds + 40960;

  // ---- node-range assignment (edge-balanced, rounded to node boundaries) ----
  const int wgl = blockIdx.x * 16 + wid;
  const int W = gridDim.x * 16;
  const int n0 = lbound(row_start, N, (long)wgl * E / W);
  const int n1 = lbound(row_start, N, (long)(wgl + 1) * E / W);
  const int pstart = row_start[n0];
  const int pend = row_start[n1];

  float4 xa, xb, ya, yb; int dstA = -1;
  if (pstart < pend) load_tile(pstart, pend, edlist, x, ea, lane, xa, xb, ya, yb, dstA);

  float carry[8];
#pragma unroll
  for (int t = 0; t < 8; ++t) carry[t] = 0.f;
  int cDst = -1, cCnt = 0;

  for (int pbase = pstart; pbase < pend; pbase += 16) {
    // ---- stage H0 = concat(x[dst], edge_attr) as bf16 [16][64] ----
    uint4 hx, he;
    hx.x = pack_bf2(xa.x, xa.y); hx.y = pack_bf2(xa.z, xa.w);
    hx.z = pack_bf2(xb.x, xb.y); hx.w = pack_bf2(xb.z, xb.w);
    he.x = pack_bf2(ya.x, ya.y); he.y = pack_bf2(ya.z, ya.w);
    he.z = pack_bf2(yb.x, yb.y); he.w = pack_bf2(yb.z, yb.w);
    const int e2 = lane >> 2, part = lane & 3;
    *(uint4*)(buf0 + aswz(e2, part * 8, 256)) = hx;
    *(uint4*)(buf0 + aswz(e2, 32 + part * 8, 256)) = he;

    const int curDst = dstA;

    // ---- prefetch next tile ----
    const int np = pbase + 16;
    float4 nxa, nxb, nya, nyb; int nd = -1;
    if (np < pend) load_tile(np, pend, edlist, x, ea, lane, nxa, nxb, nya, nyb, nd);
    else { nxa = make_float4(0,0,0,0); nxb = nxa; nya = nxa; nyb = nxa; }

    mlp_layer<4, 2, 256, 128>(buf0, buf1, wl1, biasLds + 0,   lane);   // 64 -> 64
    mlp_layer<8, 2, 128, 256>(buf1, buf0, wl2, biasLds + 64,  lane);   // 64 -> 128
    mlp_layer<4, 4, 256, 128>(buf0, buf1, wl3, biasLds + 192, lane);   // 128 -> 64

    // ---- layer 4 ----
    asm volatile("s_waitcnt lgkmcnt(0)" ::: "memory");
    u16x8 bf4[2];
#pragma unroll
    for (int ks = 0; ks < 2; ++ks)
      bf4[ks] = *(const u16x8*)(buf1 + aswz(li, ks * 32 + g * 8, 128));
    float vals[8];
#pragma unroll
    for (int mt = 0; mt < 2; ++mt) {
      const int n = mt * 16 + li;
      u16x8 af[2];
#pragma unroll
      for (int ks = 0; ks < 2; ++ks)
        af[ks] = *(const u16x8*)(wl4 + n * 128 + (((ks * 4 + g) ^ (li & 7)) << 4));
      const float4 bv = *(const float4*)(biasLds + 256 + mt * 16 + g * 4);
      f32x4 acc = {bv.x, bv.y, bv.z, bv.w};
      __builtin_amdgcn_s_setprio(1);
#pragma unroll
      for (int ks = 0; ks < 2; ++ks)
        acc = __builtin_amdgcn_mfma_f32_16x16x32_bf16(
            __builtin_bit_cast(bf16x8, af[ks]), __builtin_bit_cast(bf16x8, bf4[ks]),
            acc, 0, 0, 0);
      __builtin_amdgcn_s_setprio(0);
#pragma unroll
      for (int r = 0; r < 4; ++r) vals[mt * 4 + r] = fmaxf(acc[r], 0.f);
    }

    // ---- aggregation: fast path (whole tile continues the open node) ----
    if (__all(curDst == cDst)) {
#pragma unroll
      for (int t = 0; t < 8; ++t) carry[t] += vals[t];
      cCnt += 16;
    } else {
      const int prev = __shfl_up(curDst, 1, 16);
      const bool is_head = (li == 0) || (prev != curDst);
      const unsigned long long hb = __ballot(is_head);
      const unsigned gm = (unsigned)((hb >> (g * 16)) & 0xFFFFu);
      const unsigned below = gm & ((1u << li) | ((1u << li) - 1u));
      const int dist = li - (31 - __clz(below));

      float ctot[8];
#pragma unroll
      for (int t = 0; t < 8; ++t) {
        float c = carry[t];
#pragma unroll
        for (int d = 1; d < 16; d <<= 1) c += __shfl_xor(c, d, 16);
        ctot[t] = c;
      }

      const int dst0 = __shfl(curDst, lane & 48, 64);
      if (cDst >= 0 && dst0 != cDst && li == 0) {
        const float inv = 1.0f / (float)cCnt;
        float4 o0 = {ctot[0] * inv, ctot[1] * inv, ctot[2] * inv, ctot[3] * inv};
        float4 o1 = {ctot[4] * inv, ctot[5] * inv, ctot[6] * inv, ctot[7] * inv};
        *(float4*)(out + (size_t)cDst * 32 + g * 4) = o0;
        *(float4*)(out + (size_t)cDst * 32 + 16 + g * 4) = o1;
      }

#pragma unroll
      for (int d = 1; d < 16; d <<= 1) {
#pragma unroll
        for (int t = 0; t < 8; ++t) {
          const float tv = __shfl_up(vals[t], d, 16);
          if (dist >= d) vals[t] += tv;
        }
      }

      const int ndst0 = __shfl(nd, lane & 48, 64);
      const bool is_end = (li == 15) || ((gm >> (li + 1)) & 1u);
      const bool complete = (li < 15) || (curDst != ndst0);
      const bool firstAdd = (dist == li) && (curDst == cDst) && (cDst >= 0);
      if (is_end && curDst >= 0 && complete) {
        const int cnt = dist + 1 + (firstAdd ? cCnt : 0);
        const float inv = 1.0f / (float)cnt;
        float tot[8];
#pragma unroll
        for (int t = 0; t < 8; ++t) tot[t] = (vals[t] + (firstAdd ? ctot[t] : 0.f)) * inv;
        float4 o0 = {tot[0], tot[1], tot[2], tot[3]};
        float4 o1 = {tot[4], tot[5], tot[6], tot[7]};
        *(float4*)(out + (size_t)curDst * 32 + g * 4) = o0;
        *(float4*)(out + (size_t)curDst * 32 + 16 + g * 4) = o1;
      }

      const int dst15 = __shfl(curDst, lane | 15, 64);
      const int d15 = __shfl(dist, lane | 15, 64);
      const bool inc15 = (dst15 >= 0) && (dst15 == ndst0);
      if (inc15) {
#pragma unroll
        for (int t = 0; t < 8; ++t)
          carry[t] = (li == 15) ? (vals[t] + (firstAdd ? ctot[t] : 0.f)) : 0.f;
        cCnt = d15 + 1 + ((d15 == 15 && dst15 == cDst) ? cCnt : 0);
        cDst = dst15;
      } else {
#pragma unroll
        for (int t = 0; t < 8; ++t) carry[t] = 0.f;
        cCnt = 0; cDst = -1;
      }
    }

    xa = nxa; xb = nxb; ya = nya; yb = nyb; dstA = nd;
  }

  // ---- final flush of an open node ----
  if (cDst >= 0) {
    float ctot[8];
#pragma unroll
    for (int t = 0; t < 8; ++t) {
      float c = carry[t];
#pragma unroll
      for (int d = 1; d < 16; d <<= 1) c += __shfl_xor(c, d, 16);
      ctot[t] = c;
    }
    if (li == 0) {
      const float inv = 1.0f / (float)cCnt;
      float4 o0 = {ctot[0] * inv, ctot[1] * inv, ctot[2] * inv, ctot[3] * inv};
      float4 o1 = {ctot[4] * inv, ctot[5] * inv, ctot[6] * inv, ctot[7] * inv};
      *(float4*)(out + (size_t)cDst * 32 + g * 4) = o0;
      *(float4*)(out + (size_t)cDst * 32 + 16 + g * 4) = o1;
    }
  }
}

extern "C" void kernel_launch(void* const* d_in, const int* in_sizes, int n_in,
                              void* d_out, int out_size, void* d_ws, size_t ws_size,
                              hipStream_t stream) {
  const float* x  = (const float*)d_in[0];
  const int*   ei = (const int*)d_in[1];
  const float* ea = (const float*)d_in[2];
  const float* W1 = (const float*)d_in[3];
  const float* b1 = (const float*)d_in[4];
  const float* W2 = (const float*)d_in[5];
  const float* b2 = (const float*)d_in[6];
  const float* W3 = (const float*)d_in[7];
  const float* b3 = (const float*)d_in[8];
  const float* W4 = (const float*)d_in[9];
  const float* b4 = (const float*)d_in[10];
  const int N = in_sizes[0] / 32;
  const int E = in_sizes[1] / 2;
  float* out = (float*)d_out;

  char* ws = (char*)d_ws;
  size_t off = 0;
  auto alloc = [&](size_t bytes) { size_t o = off; off += (bytes + 255) & ~(size_t)255; return o; };
  size_t hist_off = alloc((size_t)N * 4);
  size_t wcnt_off = alloc((size_t)N * 4);
  int* histI      = (int*)(ws + hist_off);
  int* wcnt       = (int*)(ws + wcnt_off);
  int* row_start  = (int*)(ws + alloc((size_t)(N + 1) * 4));
  int* blockSums  = (int*)(ws + alloc(256 * 4));
  int2* edlist    = (int2*)(ws + alloc((size_t)E * 8));
  unsigned short* wt = (unsigned short*)(ws + alloc(22528 * 2));

  // one memset zeroes histI + wcnt (contiguous)
  hipMemsetAsync(ws + hist_off, 0, (wcnt_off - hist_off) + (size_t)N * 4, stream);

  prep_hist<<<2048, 256, 0, stream>>>(W1, W2, W3, W4, wt, ei, histI, E, N);
  const int nb = (N + 2047) / 2048;
  scan_blocks<<<nb, 256, 0, stream>>>(histI, row_start, blockSums, N);
  scan_add<<<(N + 255) / 256, 256, 0, stream>>>(row_start, blockSums, N, E, nb);
  fill_kernel<<<2048, 256, 0, stream>>>(ei, row_start, wcnt, edlist, out, E, N);
  gnn_main<<<512, 1024, 0, stream>>>(x, edlist, ea, wt, row_start,
                                     b1, b2, b3, b4, out, E, N);
}

// Round 11
// 314.495 us; speedup vs baseline: 1.4321x; 1.0867x over previous
//
#include <hip/hip_runtime.h>
#include <hip/hip_bf16.h>

typedef __attribute__((ext_vector_type(8))) unsigned short u16x8;
typedef __attribute__((ext_vector_type(8))) __bf16 bf16x8;
typedef __attribute__((ext_vector_type(4))) float f32x4;

// pack two f32 -> two bf16 (round-half-up): 2 adds + 1 v_perm_b32
__device__ __forceinline__ unsigned pack_bf2(float lo, float hi) {
  unsigned a = __float_as_uint(lo) + 0x8000u;
  unsigned b = __float_as_uint(hi) + 0x8000u;
  return __builtin_amdgcn_perm(b, a, 0x07060302);
}

__device__ __forceinline__ unsigned short f2bf(float f) {
  unsigned u = __float_as_uint(f);
  return (unsigned short)((u + 0x7fffu + ((u >> 16) & 1u)) >> 16);  // RNE (prep only)
}

// swizzled byte offset into a [rows][stride bytes] bf16 buffer (16B-chunk XOR by row&7)
__device__ __forceinline__ int aswz(int row, int feat, int stride) {
  return row * stride + (((feat >> 3) ^ (row & 7)) << 4) + (feat & 7) * 2;
}

// ---- weights transpose/pack + XCD-partitioned degree histogram ----
__global__ __launch_bounds__(256)
void prep_hist(const float* __restrict__ W1, const float* __restrict__ W2,
               const float* __restrict__ W3, const float* __restrict__ W4,
               unsigned short* __restrict__ wt,
               const int* __restrict__ ei, int* __restrict__ histI, int E, int N) {
  const int tid = threadIdx.x;
  const int i = blockIdx.x * 256 + tid;
  if (i < 22528) {
    float v; int n, k, K, base;
    if (i < 4096)       { n = i >> 6, k = i & 63;  K = 64;  base = 0;     v = W1[k * 64 + n]; }
    else if (i < 12288) { int j = i - 4096;  n = j >> 6, k = j & 63;  K = 64;  base = 4096;  v = W2[k * 128 + n]; }
    else if (i < 20480) { int j = i - 12288; n = j >> 7, k = j & 127; K = 128; base = 12288; v = W3[k * 64 + n]; }
    else                { int j = i - 20480; n = j >> 6, k = j & 63;  K = 64;  base = 20480; v = W4[k * 32 + n]; }
    int o = base + n * K + ((((k >> 3) ^ (n & 7)) << 3) + (k & 7));
    wt[o] = f2bf(v);
  }
  const int xcd = blockIdx.x & 7, kblk = blockIdx.x >> 3;
  const int nchunks = gridDim.x >> 3;
  const int chunk = (E + nchunks - 1) / nchunks;
  const int eBeg = kblk * chunk;
  const int eEnd = min(eBeg + chunk, E);
  const int dLo = (int)((long)xcd * N / 8);
  const int dHi = (int)((long)(xcd + 1) * N / 8);
  for (int e = eBeg + tid; e < eEnd; e += 256) {
    const int d = ei[E + e];
    if (d >= dLo && d < dHi) atomicAdd(&histI[d], 1);
  }
}

// per-block exclusive scan of 2048 elems (256 thr x 8), write per-block totals
__global__ void scan_blocks(const int* __restrict__ histI, int* __restrict__ row_start,
                            int* __restrict__ blockSums, int N) {
  __shared__ int wsum[4];
  const int lane = threadIdx.x & 63, w = threadIdx.x >> 6;
  const int i0 = blockIdx.x * 2048 + threadIdx.x * 8;
  int v[8];
#pragma unroll
  for (int j = 0; j < 8; ++j) { int i = i0 + j; v[j] = (i < N) ? histI[i] : 0; }
  int s = 0;
#pragma unroll
  for (int j = 0; j < 8; ++j) { int t = v[j]; v[j] = s; s += t; }
  int ss = s;
#pragma unroll
  for (int d = 1; d < 64; d <<= 1) { int t = __shfl_up(ss, d, 64); if (lane >= d) ss += t; }
  if (lane == 63) wsum[w] = ss;
  __syncthreads();
  int wOff = 0;
#pragma unroll
  for (int k = 0; k < 4; ++k) if (k < w) wOff += wsum[k];
  const int tOff = wOff + (ss - s);
#pragma unroll
  for (int j = 0; j < 8; ++j) { int i = i0 + j; if (i < N) row_start[i] = tOff + v[j]; }
  if (threadIdx.x == 255) blockSums[blockIdx.x] = wOff + ss;
}

// ---- XCD-partitioned CSR fill (block-prefix in shared) + zero out ----
__global__ __launch_bounds__(256)
void fill_kernel(const int* __restrict__ ei, const int* __restrict__ row_start,
                 const int* __restrict__ blockSums, int* __restrict__ wcnt,
                 int2* __restrict__ edlist, float* __restrict__ out,
                 int E, int N, int nb) {
  __shared__ int spre[32];
  if (threadIdx.x == 0) {
    int acc = 0;
    for (int k = 0; k < nb; ++k) { spre[k] = acc; acc += blockSums[k]; }
  }
  __syncthreads();
  const int tid = threadIdx.x;
  const int Ntot4 = N * 8;
  for (int i = blockIdx.x * 256 + tid; i < Ntot4; i += gridDim.x * 256)
    ((float4*)out)[i] = make_float4(0.f, 0.f, 0.f, 0.f);

  const int xcd = blockIdx.x & 7, kblk = blockIdx.x >> 3;
  const int nchunks = gridDim.x >> 3;
  const int chunk = (E + nchunks - 1) / nchunks;
  const int eBeg = kblk * chunk;
  const int eEnd = min(eBeg + chunk, E);
  const int dLo = (int)((long)xcd * N / 8);
  const int dHi = (int)((long)(xcd + 1) * N / 8);
  for (int e = eBeg + tid; e < eEnd; e += 256) {
    const int d = ei[E + e];
    if (d >= dLo && d < dHi) {
      const int slot = atomicAdd(&wcnt[d], 1);
      edlist[row_start[d] + spre[d >> 11] + slot] = make_int2(e, d);
    }
  }
}

// ---- one MLP layer: dst = relu(W^T srcH + b); weights read from LDS ----
template <int MT, int KS, int SS, int DS>
__device__ __forceinline__ void mlp_layer(const unsigned char* src, unsigned char* dst,
                                          const unsigned char* wl, const float* biasL, int lane) {
  const int edge = lane & 15, g = lane >> 4;
  asm volatile("s_waitcnt lgkmcnt(0)" ::: "memory");
  u16x8 bfrag[KS];
#pragma unroll
  for (int ks = 0; ks < KS; ++ks)
    bfrag[ks] = *(const u16x8*)(src + aswz(edge, ks * 32 + g * 8, SS));
#pragma unroll
  for (int mt = 0; mt < MT; ++mt) {
    const int n = mt * 16 + edge;
    u16x8 af[KS];
#pragma unroll
    for (int ks = 0; ks < KS; ++ks)
      af[ks] = *(const u16x8*)(wl + n * (KS * 64) + (((ks * 4 + g) ^ (edge & 7)) << 4));
    const float4 bv = *(const float4*)(biasL + mt * 16 + g * 4);
    f32x4 acc = {bv.x, bv.y, bv.z, bv.w};
    __builtin_amdgcn_s_setprio(1);
#pragma unroll
    for (int ks = 0; ks < KS; ++ks)
      acc = __builtin_amdgcn_mfma_f32_16x16x32_bf16(
          __builtin_bit_cast(bf16x8, af[ks]), __builtin_bit_cast(bf16x8, bfrag[ks]),
          acc, 0, 0, 0);
    __builtin_amdgcn_s_setprio(0);
    const int fb = mt * 16 + g * 4;
    uint2 q;
    q.x = pack_bf2(fmaxf(acc[0], 0.f), fmaxf(acc[1], 0.f));
    q.y = pack_bf2(fmaxf(acc[2], 0.f), fmaxf(acc[3], 0.f));
    *(uint2*)(dst + aswz(edge, fb, DS)) = q;
  }
}

// prefetch one 16-edge tile's gather into registers (+ degree for mean fusion)
__device__ __forceinline__ void load_tile(int ebase, int E, const int2* __restrict__ edlist,
                                          const float* __restrict__ x, const float* __restrict__ ea,
                                          const int* __restrict__ histI,
                                          int lane, float4& xa, float4& xb, float4& ya, float4& yb,
                                          int& dstA, int& cntA) {
  const int el = ebase + (lane >> 2);
  const int part = lane & 3;
  xa = make_float4(0.f, 0.f, 0.f, 0.f); xb = xa; ya = xa; yb = xa;
  if (el < E) {
    const int2 ed = edlist[el];
    const float4* xp = (const float4*)(x + (size_t)ed.y * 32 + part * 8);
    xa = xp[0]; xb = xp[1];
    const float4* ep = (const float4*)(ea + (size_t)ed.x * 32 + part * 8);
    ya = ep[0]; yb = ep[1];
  }
  const int pos = ebase + (lane & 15);
  dstA = -1; cntA = 1;
  if (pos < E) {
    dstA = edlist[pos].y;
    cntA = histI[dstA];
  }
}

// LDS layout: [weights 45056][bias 1152][16 waves x (buf0 4096 + buf1 2048)]
#define BIAS_OFF 45056
#define ACT_OFF  46208

__global__ __launch_bounds__(1024, 4)
void gnn_main(const float* __restrict__ x, const int2* __restrict__ edlist,
              const float* __restrict__ ea, const unsigned short* __restrict__ wt,
              const int* __restrict__ histI,
              const float* __restrict__ b1, const float* __restrict__ b2,
              const float* __restrict__ b3, const float* __restrict__ b4,
              float* __restrict__ out, int E, int numTiles) {
  __shared__ __align__(16) unsigned char lds[ACT_OFF + 16 * 6144];
  {
    const u16x8* gw = (const u16x8*)wt;
    u16x8* lw = (u16x8*)lds;
    for (int i = threadIdx.x; i < 2816; i += 1024) lw[i] = gw[i];
    float* biasW = (float*)(lds + BIAS_OFF);
    for (int i = threadIdx.x; i < 288; i += 1024) {
      float v;
      if (i < 64) v = b1[i];
      else if (i < 192) v = b2[i - 64];
      else if (i < 256) v = b3[i - 192];
      else v = b4[i - 256];
      biasW[i] = v;
    }
  }
  __syncthreads();

  const int lane = threadIdx.x & 63, wid = threadIdx.x >> 6;
  const int li = lane & 15, g = lane >> 4;
  const float* biasLds = (const float*)(lds + BIAS_OFF);
  unsigned char* buf0 = lds + ACT_OFF + wid * 6144;
  unsigned char* buf1 = buf0 + 4096;
  const unsigned char* wl1 = lds;
  const unsigned char* wl2 = lds + 8192;
  const unsigned char* wl3 = lds + 24576;
  const unsigned char* wl4 = lds + 40960;

  const int wgl = blockIdx.x * 16 + wid;
  const int wstride = gridDim.x * 16;

  float4 xa, xb, ya, yb; int dstA = -1, cntA = 1;
  if (wgl < numTiles) load_tile(wgl * 16, E, edlist, x, ea, histI, lane, xa, xb, ya, yb, dstA, cntA);

  for (int tile = wgl; tile < numTiles; tile += wstride) {
    // ---- stage H0 = concat(x[dst], edge_attr) as bf16 [16][64] ----
    uint4 hx, he;
    hx.x = pack_bf2(xa.x, xa.y); hx.y = pack_bf2(xa.z, xa.w);
    hx.z = pack_bf2(xb.x, xb.y); hx.w = pack_bf2(xb.z, xb.w);
    he.x = pack_bf2(ya.x, ya.y); he.y = pack_bf2(ya.z, ya.w);
    he.z = pack_bf2(yb.x, yb.y); he.w = pack_bf2(yb.z, yb.w);
    const int e2 = lane >> 2, part = lane & 3;
    *(uint4*)(buf0 + aswz(e2, part * 8, 256)) = hx;
    *(uint4*)(buf0 + aswz(e2, 32 + part * 8, 256)) = he;

    const int curDst = dstA, curCnt = cntA;

    // ---- issue next tile's gather; drains under the MFMA chain ----
    const int nt = tile + wstride;
    float4 nxa, nxb, nya, nyb; int nd = -1, nc = 1;
    if (nt < numTiles) load_tile(nt * 16, E, edlist, x, ea, histI, lane, nxa, nxb, nya, nyb, nd, nc);
    else { nxa = make_float4(0,0,0,0); nxb = nxa; nya = nxa; nyb = nxa; }

    mlp_layer<4, 2, 256, 128>(buf0, buf1, wl1, biasLds + 0,   lane);   // 64 -> 64
    mlp_layer<8, 2, 128, 256>(buf1, buf0, wl2, biasLds + 64,  lane);   // 64 -> 128
    mlp_layer<4, 4, 256, 128>(buf0, buf1, wl3, biasLds + 192, lane);   // 128 -> 64

    // ---- layer 4 + segmented lane-reduce + mean-scaled sparse atomics ----
    asm volatile("s_waitcnt lgkmcnt(0)" ::: "memory");
    u16x8 bf4[2];
#pragma unroll
    for (int ks = 0; ks < 2; ++ks)
      bf4[ks] = *(const u16x8*)(buf1 + aswz(li, ks * 32 + g * 8, 128));
    float vals[8];
#pragma unroll
    for (int mt = 0; mt < 2; ++mt) {
      const int n = mt * 16 + li;
      u16x8 af[2];
#pragma unroll
      for (int ks = 0; ks < 2; ++ks)
        af[ks] = *(const u16x8*)(wl4 + n * 128 + (((ks * 4 + g) ^ (li & 7)) << 4));
      const float4 bv = *(const float4*)(biasLds + 256 + mt * 16 + g * 4);
      f32x4 acc = {bv.x, bv.y, bv.z, bv.w};
      __builtin_amdgcn_s_setprio(1);
#pragma unroll
      for (int ks = 0; ks < 2; ++ks)
        acc = __builtin_amdgcn_mfma_f32_16x16x32_bf16(
            __builtin_bit_cast(bf16x8, af[ks]), __builtin_bit_cast(bf16x8, bf4[ks]),
            acc, 0, 0, 0);
      __builtin_amdgcn_s_setprio(0);
#pragma unroll
      for (int r = 0; r < 4; ++r) vals[mt * 4 + r] = fmaxf(acc[r], 0.f);
    }

    // segmented sum across the 16-edge lane dim (CSR order => equal dsts adjacent)
    const int prev = __shfl_up(curDst, 1, 16);
    const bool is_head = (li == 0) || (prev != curDst);
    const unsigned long long hb = __ballot(is_head);
    const unsigned gm = (unsigned)((hb >> (g * 16)) & 0xFFFFu);
    const unsigned below = gm & ((1u << li) | ((1u << li) - 1u));
    const int dist = li - (31 - __clz(below));
#pragma unroll
    for (int d = 1; d < 16; d <<= 1) {
#pragma unroll
      for (int t = 0; t < 8; ++t) {
        const float tv = __shfl_up(vals[t], d, 16);
        if (dist >= d) vals[t] += tv;
      }
    }
    const bool is_end = (li == 15) || ((gm >> (li + 1)) & 1u);
    if (is_end && curDst >= 0) {
      const float inv = 1.0f / (float)curCnt;   // mean fused into scatter
      float* op = out + (size_t)curDst * 32 + g * 4;
#pragma unroll
      for (int t = 0; t < 4; ++t) unsafeAtomicAdd(op + t, vals[t] * inv);
#pragma unroll
      for (int t = 0; t < 4; ++t) unsafeAtomicAdd(op + 16 + t, vals[4 + t] * inv);
    }

    xa = nxa; xb = nxb; ya = nya; yb = nyb; dstA = nd; cntA = nc;
  }
}

extern "C" void kernel_launch(void* const* d_in, const int* in_sizes, int n_in,
                              void* d_out, int out_size, void* d_ws, size_t ws_size,
                              hipStream_t stream) {
  const float* x  = (const float*)d_in[0];
  const int*   ei = (const int*)d_in[1];
  const float* ea = (const float*)d_in[2];
  const float* W1 = (const float*)d_in[3];
  const float* b1 = (const float*)d_in[4];
  const float* W2 = (const float*)d_in[5];
  const float* b2 = (const float*)d_in[6];
  const float* W3 = (const float*)d_in[7];
  const float* b3 = (const float*)d_in[8];
  const float* W4 = (const float*)d_in[9];
  const float* b4 = (const float*)d_in[10];
  const int N = in_sizes[0] / 32;
  const int E = in_sizes[1] / 2;
  float* out = (float*)d_out;

  char* ws = (char*)d_ws;
  size_t off = 0;
  auto alloc = [&](size_t bytes) { size_t o = off; off += (bytes + 255) & ~(size_t)255; return o; };
  size_t hist_off = alloc((size_t)N * 4);
  size_t wcnt_off = alloc((size_t)N * 4);
  int* histI      = (int*)(ws + hist_off);
  int* wcnt       = (int*)(ws + wcnt_off);
  int* row_start  = (int*)(ws + alloc((size_t)(N + 1) * 4));
  int* blockSums  = (int*)(ws + alloc(256 * 4));
  int2* edlist    = (int2*)(ws + alloc((size_t)E * 8));
  unsigned short* wt = (unsigned short*)(ws + alloc(22528 * 2));

  // one memset zeroes histI + wcnt (contiguous)
  hipMemsetAsync(ws + hist_off, 0, (wcnt_off - hist_off) + (size_t)N * 4, stream);

  prep_hist<<<2048, 256, 0, stream>>>(W1, W2, W3, W4, wt, ei, histI, E, N);
  const int nb = (N + 2047) / 2048;
  scan_blocks<<<nb, 256, 0, stream>>>(histI, row_start, blockSums, N);
  fill_kernel<<<2048, 256, 0, stream>>>(ei, row_start, blockSums, wcnt, edlist, out, E, N, nb);
  const int numTiles = (E + 15) / 16;
  gnn_main<<<256, 1024, 0, stream>>>(x, edlist, ea, wt, histI,
                                     b1, b2, b3, b4, out, E, numTiles);
}